// Round 6
// baseline (819.525 us; speedup 1.0000x reference)
//
#include <hip/hip_runtime.h>

#define NN 50000      // N_ENT
#define NR 100        // N_REL2
#define NB 16         // N_BASES
#define D  64         // DIM
#define NE 100000     // N_EDGES

#define HB  196       // histogram/scatter blocks
#define EPB 512       // edges per block in hist/scatter

#define CHUNK 64      // edges per edge-kernel block (4 waves x 16)
#define EGRID 2048    // max chunks (sum ceil(len_r/64) <= 100000/64+100 = 1663)

#define NPB 32        // nodes per node-kernel block (4 waves x 8)
#define NGRID ((NN + NPB - 1) / NPB)

typedef float f32x4 __attribute__((ext_vector_type(4)));

// Fused weight prep. Blocks 0..199: Wt[layer][r][d][k] = sum_b att[r,b]*basis[b,k,d]
// (transposed via padded-LDS). Blocks 200..201: rT[d][k] = root[k][d].
__global__ __launch_bounds__(256) void compute_wt(
    const float* __restrict__ att1, const float* __restrict__ basis1,
    const float* __restrict__ root1,
    const float* __restrict__ att2, const float* __restrict__ basis2,
    const float* __restrict__ root2,
    float* __restrict__ Wt1, float* __restrict__ Wt2,
    float* __restrict__ rT1, float* __restrict__ rT2)
{
    __shared__ float t[64 * 65];
    int b = blockIdx.x;
    if (b < 2 * NR) {
        int layer = b >= NR;
        int r = layer ? b - NR : b;
        const float* att   = layer ? att2 : att1;
        const float* basis = layer ? basis2 : basis1;
        float*       Wt    = layer ? Wt2 : Wt1;
        float a[NB];
#pragma unroll
        for (int bb = 0; bb < NB; ++bb) a[bb] = att[r * NB + bb];
#pragma unroll
        for (int i = 0; i < 16; ++i) {
            int idx = i * 256 + threadIdx.x;        // [k][d] linear
            float acc = 0.f;
#pragma unroll
            for (int bb = 0; bb < NB; ++bb) acc += a[bb] * basis[bb * 4096 + idx];
            t[(idx >> 6) * 65 + (idx & 63)] = acc;  // t[k][d], padded
        }
        __syncthreads();
#pragma unroll
        for (int i = 0; i < 16; ++i) {
            int j = i * 256 + threadIdx.x;          // [d][k] linear
            Wt[(size_t)r * 4096 + j] = t[(j & 63) * 65 + (j >> 6)];
        }
    } else {
        const float* root = (b == 2 * NR) ? root1 : root2;
        float*       rT   = (b == 2 * NR) ? rT1 : rT2;
#pragma unroll
        for (int i = 0; i < 16; ++i) {
            int idx = i * 256 + threadIdx.x;
            t[(idx >> 6) * 65 + (idx & 63)] = root[idx];
        }
        __syncthreads();
#pragma unroll
        for (int i = 0; i < 16; ++i) {
            int j = i * 256 + threadIdx.x;
            rT[j] = t[(j & 63) * 65 + (j >> 6)];
        }
    }
}

// x0[n, :] = emb[entity[n], :]  (float4 vectorized)
__global__ __launch_bounds__(256) void gather_emb(
    const int* __restrict__ entity, const f32x4* __restrict__ emb4,
    f32x4* __restrict__ x04)
{
    int idx = blockIdx.x * 256 + threadIdx.x;      // over NN*16
    if (idx >= NN * 16) return;
    int n = idx >> 4;
    int q = idx & 15;
    x04[idx] = emb4[(size_t)entity[n] * 16 + q];
}

// Pass 1: per-block relation histogram (LDS atomics) + node in-degree
__global__ __launch_bounds__(256) void hist_edges(
    const int* __restrict__ et, const int* __restrict__ dst,
    int* __restrict__ blockHist, float* __restrict__ cnt)
{
    __shared__ int lh[NR];
    for (int i = threadIdx.x; i < NR; i += 256) lh[i] = 0;
    __syncthreads();
#pragma unroll
    for (int i = 0; i < EPB / 256; ++i) {
        int e = blockIdx.x * EPB + i * 256 + threadIdx.x;
        if (e < NE) {
            atomicAdd(&lh[et[e]], 1);
            atomicAdd(&cnt[dst[e]], 1.0f);
        }
    }
    __syncthreads();
    for (int i = threadIdx.x; i < NR; i += 256)
        blockHist[blockIdx.x * NR + i] = lh[i];
}

// Pass 2a: per-relation column scan over the 196 block histograms.
// Block r: blockPrefix[b][r] = sum_{b'<b} blockHist[b'][r]; relTot[r] = total.
__global__ __launch_bounds__(256) void colscan(
    const int* __restrict__ blockHist, int* __restrict__ blockPrefix,
    int* __restrict__ relTot)
{
    __shared__ int sc[256];
    int r = blockIdx.x;
    int t = threadIdx.x;
    int v = (t < HB) ? blockHist[t * NR + r] : 0;
    sc[t] = v;
    __syncthreads();
#pragma unroll
    for (int off = 1; off < 256; off <<= 1) {
        int a = (t >= off) ? sc[t - off] : 0;
        __syncthreads();
        sc[t] += a;
        __syncthreads();
    }
    if (t < HB) blockPrefix[t * NR + r] = sc[t] - v;   // exclusive
    if (t == 0) relTot[r] = sc[255];
}

// Pass 2b: tiny single-block: relation offsets, chunk-count prefix, chunk table.
__global__ __launch_bounds__(256) void scanK(
    const int* __restrict__ relTot, int* __restrict__ offs,
    int* __restrict__ nbG, int* __restrict__ tabR, int* __restrict__ tabS)
{
    __shared__ int totL[NR];
    __shared__ int offL[NR + 1];
    __shared__ int cnbL[NR + 1];
    int t = threadIdx.x;
    if (t < NR) totL[t] = relTot[t];
    __syncthreads();
    if (t == 0) {
        int off = 0, cb = 0;
        for (int r = 0; r < NR; ++r) {
            offL[r] = off; cnbL[r] = cb;
            off += totL[r];
            cb  += (totL[r] + CHUNK - 1) / CHUNK;
        }
        offL[NR] = off; cnbL[NR] = cb;
    }
    __syncthreads();
    if (t <= NR) offs[t] = offL[t];
    if (t == 0) nbG[0] = cnbL[NR];
    int nb = cnbL[NR];
    for (int e = t; e < nb; e += 256) {
        int lo = 0, hi = NR;                      // find r: cnbL[r] <= e < cnbL[r+1]
        while (hi - lo > 1) { int mid = (lo + hi) >> 1; if (cnbL[mid] <= e) lo = mid; else hi = mid; }
        tabR[e] = lo;
        tabS[e] = offL[lo] + (e - cnbL[lo]) * CHUNK;
    }
}

// Pass 3: scatter edges into relation-sorted arrays (LDS cursors only)
__global__ __launch_bounds__(256) void scatter_sorted(
    const int* __restrict__ src, const int* __restrict__ dst,
    const int* __restrict__ et, const float* __restrict__ en,
    const int* __restrict__ offs, const int* __restrict__ blockPrefix,
    int* __restrict__ srcS, int* __restrict__ dstS, float* __restrict__ normS)
{
    __shared__ int lcur[NR];
    for (int i = threadIdx.x; i < NR; i += 256)
        lcur[i] = offs[i] + blockPrefix[blockIdx.x * NR + i];
    __syncthreads();
#pragma unroll
    for (int i = 0; i < EPB / 256; ++i) {
        int e = blockIdx.x * EPB + i * 256 + threadIdx.x;
        if (e < NE) {
            int r = et[e];
            int p = atomicAdd(&lcur[r], 1);
            srcS[p] = src[e]; dstS[p] = dst[e]; normS[p] = en[e];
        }
    }
}

// Edge kernel: one block per (relation, 64-edge chunk). W[r] staged in LDS
// once per block with XOR bank swizzle; 4-edge unroll shares each ds_read_b128
// across 4 edges' FMAs. x-row broadcast via v_readlane. Tail edges masked.
__global__ __launch_bounds__(256, 8) void edge_lds(
    const int* __restrict__ srcS, const int* __restrict__ dstS,
    const float* __restrict__ normS, const int* __restrict__ offs,
    const int* __restrict__ tabR, const int* __restrict__ tabS,
    const int* __restrict__ nbG, const float* __restrict__ x,
    const float* __restrict__ Wt, float* __restrict__ s)
{
    __shared__ f32x4 WL4[1024];                    // 16 KB
    int b = blockIdx.x;
    if (b >= nbG[0]) return;
    int r  = tabR[b];
    int cs = tabS[b];
    int tid = threadIdx.x;

    // stage Wt[r] (d-major rows) with slot swizzle: slot = g ^ (d&7)
    {
        const f32x4* __restrict__ Wg = (const f32x4*)(Wt + (size_t)r * 4096);
#pragma unroll
        for (int i = 0; i < 4; ++i) {
            int idx = tid + i * 256;               // f32x4 index 0..1023
            f32x4 v = Wg[idx];
            int d = idx >> 4, g = idx & 15;
            *(f32x4*)((char*)WL4 + ((d << 8) | ((g ^ (d & 7)) << 4))) = v;
        }
    }
    __syncthreads();

    int wid  = tid >> 6;
    int lane = tid & 63;
    int wstart = cs + wid * 16;
    int wend   = cs + CHUNK;
    int segE   = offs[r + 1];
    if (segE < wend) wend = segE;
    int cw = wend - wstart;
    if (cw <= 0) return;
    if (cw > 16) cw = 16;

    int ei   = wstart + (lane < cw ? lane : 0);    // lane i holds meta of edge wstart+i
    int srcv = srcS[ei];
    int dstv = dstS[ei];
    int nrmv = __float_as_int(normS[ei]);

    const int base = (lane << 8) | ((lane & 7) << 4);

    float xv0 = x[(size_t)__builtin_amdgcn_readlane(srcv, 0) * 64 + lane];
    float xv1 = x[(size_t)__builtin_amdgcn_readlane(srcv, 1) * 64 + lane];
    float xv2 = x[(size_t)__builtin_amdgcn_readlane(srcv, 2) * 64 + lane];
    float xv3 = x[(size_t)__builtin_amdgcn_readlane(srcv, 3) * 64 + lane];

    for (int g0 = 0; g0 < cw; g0 += 4) {
        int xc[4];
        xc[0] = __float_as_int(xv0); xc[1] = __float_as_int(xv1);
        xc[2] = __float_as_int(xv2); xc[3] = __float_as_int(xv3);
        int dn[4]; float nm[4];
#pragma unroll
        for (int j = 0; j < 4; ++j) {
            dn[j] = __builtin_amdgcn_readlane(dstv, g0 + j);
            nm[j] = __int_as_float(__builtin_amdgcn_readlane(nrmv, g0 + j));
        }
        if (g0 + 4 < cw) {
            xv0 = x[(size_t)__builtin_amdgcn_readlane(srcv, g0 + 4) * 64 + lane];
            xv1 = x[(size_t)__builtin_amdgcn_readlane(srcv, g0 + 5) * 64 + lane];
            xv2 = x[(size_t)__builtin_amdgcn_readlane(srcv, g0 + 6) * 64 + lane];
            xv3 = x[(size_t)__builtin_amdgcn_readlane(srcv, g0 + 7) * 64 + lane];
        }
        float a[4][4] = {{0.f}};
#pragma unroll
        for (int t = 0; t < 16; ++t) {
            f32x4 ww = *(const f32x4*)((const char*)WL4 + (base ^ (t << 4)));
#pragma unroll
            for (int j = 0; j < 4; ++j) {
                a[j][0] = fmaf(__int_as_float(__builtin_amdgcn_readlane(xc[j], 4 * t + 0)), ww.x, a[j][0]);
                a[j][1] = fmaf(__int_as_float(__builtin_amdgcn_readlane(xc[j], 4 * t + 1)), ww.y, a[j][1]);
                a[j][2] = fmaf(__int_as_float(__builtin_amdgcn_readlane(xc[j], 4 * t + 2)), ww.z, a[j][2]);
                a[j][3] = fmaf(__int_as_float(__builtin_amdgcn_readlane(xc[j], 4 * t + 3)), ww.w, a[j][3]);
            }
        }
#pragma unroll
        for (int j = 0; j < 4; ++j)
            if (g0 + j < cw)
                atomicAdd(&s[(size_t)dn[j] * 64 + lane],
                          ((a[j][0] + a[j][1]) + (a[j][2] + a[j][3])) * nm[j]);
    }
}

// Node kernel: rT staged in LDS (same swizzle), 8 nodes/wave (2 groups of 4).
// NN % 8 == 0 so active waves have full groups. In-place-safe (x == out).
__global__ __launch_bounds__(256, 8) void node_lds(
    const float* __restrict__ x, float* __restrict__ s,
    const float* __restrict__ cnt, const float* __restrict__ rT,
    const float* __restrict__ bias, float* __restrict__ out, int zero_s)
{
    __shared__ f32x4 RL4[1024];                    // 16 KB
    int tid = threadIdx.x;
    {
        const f32x4* __restrict__ Rg = (const f32x4*)rT;
#pragma unroll
        for (int i = 0; i < 4; ++i) {
            int idx = tid + i * 256;
            f32x4 v = Rg[idx];
            int d = idx >> 4, g = idx & 15;
            *(f32x4*)((char*)RL4 + ((d << 8) | ((g ^ (d & 7)) << 4))) = v;
        }
    }
    __syncthreads();

    int wid  = tid >> 6;
    int lane = tid & 63;
    int n0 = blockIdx.x * NPB + wid * 8;
    if (n0 >= NN) return;

    const int base = (lane << 8) | ((lane & 7) << 4);
    float bv = bias[lane];

#pragma unroll
    for (int gq = 0; gq < 2; ++gq) {
        int n = n0 + gq * 4;
        int xc[4]; float sv[4], cv[4];
#pragma unroll
        for (int j = 0; j < 4; ++j) {
            xc[j] = __float_as_int(x[(size_t)(n + j) * 64 + lane]);
            sv[j] = s[(size_t)(n + j) * 64 + lane];
            cv[j] = cnt[n + j];
        }
        float a[4][4] = {{0.f}};
#pragma unroll
        for (int t = 0; t < 16; ++t) {
            f32x4 ww = *(const f32x4*)((const char*)RL4 + (base ^ (t << 4)));
#pragma unroll
            for (int j = 0; j < 4; ++j) {
                a[j][0] = fmaf(__int_as_float(__builtin_amdgcn_readlane(xc[j], 4 * t + 0)), ww.x, a[j][0]);
                a[j][1] = fmaf(__int_as_float(__builtin_amdgcn_readlane(xc[j], 4 * t + 1)), ww.y, a[j][1]);
                a[j][2] = fmaf(__int_as_float(__builtin_amdgcn_readlane(xc[j], 4 * t + 2)), ww.z, a[j][2]);
                a[j][3] = fmaf(__int_as_float(__builtin_amdgcn_readlane(xc[j], 4 * t + 3)), ww.w, a[j][3]);
            }
        }
#pragma unroll
        for (int j = 0; j < 4; ++j) {
            float c = cv[j] > 1.f ? cv[j] : 1.f;
            out[(size_t)(n + j) * 64 + lane] =
                sv[j] / c + ((a[j][0] + a[j][1]) + (a[j][2] + a[j][3])) + bv;
            if (zero_s) s[(size_t)(n + j) * 64 + lane] = 0.f;
        }
    }
}

extern "C" void kernel_launch(void* const* d_in, const int* in_sizes, int n_in,
                              void* d_out, int out_size, void* d_ws, size_t ws_size,
                              hipStream_t stream) {
    const int*   entity    = (const int*)d_in[0];
    const int*   edge_index= (const int*)d_in[1];    // [2, NE]
    const int*   edge_type = (const int*)d_in[2];
    const float* edge_norm = (const float*)d_in[3];
    const float* emb       = (const float*)d_in[4];
    const float* basis1    = (const float*)d_in[5];
    const float* att1      = (const float*)d_in[6];
    const float* root1     = (const float*)d_in[7];
    const float* bias1     = (const float*)d_in[8];
    const float* basis2    = (const float*)d_in[9];
    const float* att2      = (const float*)d_in[10];
    const float* root2     = (const float*)d_in[11];
    const float* bias2     = (const float*)d_in[12];

    const int* src = edge_index;
    const int* dst = edge_index + NE;

    // float arrays first (16B alignment for f32x4 loads), ints at the end
    float* ws    = (float*)d_ws;
    float* Wt1   = ws;                           // NR*4096
    float* Wt2   = Wt1 + (size_t)NR * 4096;      // NR*4096
    float* rT1   = Wt2 + (size_t)NR * 4096;      // 4096
    float* rT2   = rT1 + 4096;                   // 4096
    float* x0    = rT2 + 4096;                   // NN*D
    float* s     = x0  + (size_t)NN * D;         // NN*D
    float* cnt   = s   + (size_t)NN * D;         // NN
    float* normS = cnt + NN;                     // NE
    int*   offs        = (int*)(normS + NE);     // NR+1 (+pad)
    int*   relTot      = offs + NR + 3;          // NR
    int*   nbG         = relTot + NR;            // 1 (+pad)
    int*   blockHist   = nbG + 3;                // HB*NR
    int*   blockPrefix = blockHist + HB * NR;    // HB*NR
    int*   tabR        = blockPrefix + HB * NR;  // EGRID
    int*   tabS        = tabR + EGRID;           // EGRID
    int*   srcS        = tabS + EGRID;           // NE
    int*   dstS        = srcS + NE;              // NE

    float* out = (float*)d_out;

    // zero s + cnt (contiguous)
    hipMemsetAsync(s, 0, ((size_t)NN * D + NN) * sizeof(float), stream);

    compute_wt<<<2 * NR + 2, 256, 0, stream>>>(att1, basis1, root1,
                                               att2, basis2, root2,
                                               Wt1, Wt2, rT1, rT2);
    gather_emb<<<(NN * 16 + 255) / 256, 256, 0, stream>>>(
        entity, (const f32x4*)emb, (f32x4*)x0);
    hist_edges<<<HB, 256, 0, stream>>>(edge_type, dst, blockHist, cnt);
    colscan<<<NR, 256, 0, stream>>>(blockHist, blockPrefix, relTot);
    scanK<<<1, 256, 0, stream>>>(relTot, offs, nbG, tabR, tabS);
    scatter_sorted<<<HB, 256, 0, stream>>>(src, dst, edge_type, edge_norm,
                                           offs, blockPrefix, srcS, dstS, normS);

    // ---- layer 1 ----
    edge_lds<<<EGRID, 256, 0, stream>>>(srcS, dstS, normS, offs,
                                        tabR, tabS, nbG, x0, Wt1, s);
    node_lds<<<NGRID, 256, 0, stream>>>(x0, s, cnt, rT1, bias1, out, 1);

    // ---- layer 2 ----
    edge_lds<<<EGRID, 256, 0, stream>>>(srcS, dstS, normS, offs,
                                        tabR, tabS, nbG, out, Wt2, s);
    node_lds<<<NGRID, 256, 0, stream>>>(out, s, cnt, rT2, bias2, out, 0);
}

// Round 7
// 191.027 us; speedup vs baseline: 4.2901x; 4.2901x over previous
//
#include <hip/hip_runtime.h>

#define NN 50000      // N_ENT
#define NR 100        // N_REL2
#define NB 16         // N_BASES
#define D  64         // DIM
#define NE 100000     // N_EDGES

#define HB  196       // histogram/scatter blocks
#define EPB 512       // edges per block in hist/scatter

#define CHUNK 64      // edges per edge-kernel block (4 waves x 16)
#define EGRID 2048    // max chunks (sum ceil(len_r/64) <= 100000/64+100 = 1663)

#define NPB 32        // nodes per node-kernel block (4 waves x 8)
#define NGRID ((NN + NPB - 1) / NPB)

typedef float f32x4 __attribute__((ext_vector_type(4)));

// Fused weight prep. Blocks 0..199: Wt[layer][r][d][k] = sum_b att[r,b]*basis[b,k,d]
// (transposed via padded-LDS). Blocks 200..201: rT[d][k] = root[k][d].
__global__ __launch_bounds__(256) void compute_wt(
    const float* __restrict__ att1, const float* __restrict__ basis1,
    const float* __restrict__ root1,
    const float* __restrict__ att2, const float* __restrict__ basis2,
    const float* __restrict__ root2,
    float* __restrict__ Wt1, float* __restrict__ Wt2,
    float* __restrict__ rT1, float* __restrict__ rT2)
{
    __shared__ float t[64 * 65];
    int b = blockIdx.x;
    if (b < 2 * NR) {
        int layer = b >= NR;
        int r = layer ? b - NR : b;
        const float* att   = layer ? att2 : att1;
        const float* basis = layer ? basis2 : basis1;
        float*       Wt    = layer ? Wt2 : Wt1;
        float a[NB];
#pragma unroll
        for (int bb = 0; bb < NB; ++bb) a[bb] = att[r * NB + bb];
#pragma unroll
        for (int i = 0; i < 16; ++i) {
            int idx = i * 256 + threadIdx.x;        // [k][d] linear
            float acc = 0.f;
#pragma unroll
            for (int bb = 0; bb < NB; ++bb) acc += a[bb] * basis[bb * 4096 + idx];
            t[(idx >> 6) * 65 + (idx & 63)] = acc;  // t[k][d], padded
        }
        __syncthreads();
#pragma unroll
        for (int i = 0; i < 16; ++i) {
            int j = i * 256 + threadIdx.x;          // [d][k] linear
            Wt[(size_t)r * 4096 + j] = t[(j & 63) * 65 + (j >> 6)];
        }
    } else {
        const float* root = (b == 2 * NR) ? root1 : root2;
        float*       rT   = (b == 2 * NR) ? rT1 : rT2;
#pragma unroll
        for (int i = 0; i < 16; ++i) {
            int idx = i * 256 + threadIdx.x;
            t[(idx >> 6) * 65 + (idx & 63)] = root[idx];
        }
        __syncthreads();
#pragma unroll
        for (int i = 0; i < 16; ++i) {
            int j = i * 256 + threadIdx.x;
            rT[j] = t[(j & 63) * 65 + (j >> 6)];
        }
    }
}

// x0[n, :] = emb[entity[n], :]  (float4 vectorized)
__global__ __launch_bounds__(256) void gather_emb(
    const int* __restrict__ entity, const f32x4* __restrict__ emb4,
    f32x4* __restrict__ x04)
{
    int idx = blockIdx.x * 256 + threadIdx.x;      // over NN*16
    if (idx >= NN * 16) return;
    int n = idx >> 4;
    int q = idx & 15;
    x04[idx] = emb4[(size_t)entity[n] * 16 + q];
}

// Pass 1: per-block relation histogram (LDS atomics) + node in-degree
__global__ __launch_bounds__(256) void hist_edges(
    const int* __restrict__ et, const int* __restrict__ dst,
    int* __restrict__ blockHist, float* __restrict__ cnt)
{
    __shared__ int lh[NR];
    for (int i = threadIdx.x; i < NR; i += 256) lh[i] = 0;
    __syncthreads();
#pragma unroll
    for (int i = 0; i < EPB / 256; ++i) {
        int e = blockIdx.x * EPB + i * 256 + threadIdx.x;
        if (e < NE) {
            atomicAdd(&lh[et[e]], 1);
            atomicAdd(&cnt[dst[e]], 1.0f);
        }
    }
    __syncthreads();
    for (int i = threadIdx.x; i < NR; i += 256)
        blockHist[blockIdx.x * NR + i] = lh[i];
}

// Pass 2a: per-relation column scan over the 196 block histograms.
__global__ __launch_bounds__(256) void colscan(
    const int* __restrict__ blockHist, int* __restrict__ blockPrefix,
    int* __restrict__ relTot)
{
    __shared__ int sc[256];
    int r = blockIdx.x;
    int t = threadIdx.x;
    int v = (t < HB) ? blockHist[t * NR + r] : 0;
    sc[t] = v;
    __syncthreads();
#pragma unroll
    for (int off = 1; off < 256; off <<= 1) {
        int a = (t >= off) ? sc[t - off] : 0;
        __syncthreads();
        sc[t] += a;
        __syncthreads();
    }
    if (t < HB) blockPrefix[t * NR + r] = sc[t] - v;   // exclusive
    if (t == 0) relTot[r] = sc[255];
}

// Pass 2b: tiny single-block: relation offsets, chunk-count prefix, chunk table.
__global__ __launch_bounds__(256) void scanK(
    const int* __restrict__ relTot, int* __restrict__ offs,
    int* __restrict__ nbG, int* __restrict__ tabR, int* __restrict__ tabS)
{
    __shared__ int totL[NR];
    __shared__ int offL[NR + 1];
    __shared__ int cnbL[NR + 1];
    int t = threadIdx.x;
    if (t < NR) totL[t] = relTot[t];
    __syncthreads();
    if (t == 0) {
        int off = 0, cb = 0;
        for (int r = 0; r < NR; ++r) {
            offL[r] = off; cnbL[r] = cb;
            off += totL[r];
            cb  += (totL[r] + CHUNK - 1) / CHUNK;
        }
        offL[NR] = off; cnbL[NR] = cb;
    }
    __syncthreads();
    if (t <= NR) offs[t] = offL[t];
    if (t == 0) nbG[0] = cnbL[NR];
    int nb = cnbL[NR];
    for (int e = t; e < nb; e += 256) {
        int lo = 0, hi = NR;                      // find r: cnbL[r] <= e < cnbL[r+1]
        while (hi - lo > 1) { int mid = (lo + hi) >> 1; if (cnbL[mid] <= e) lo = mid; else hi = mid; }
        tabR[e] = lo;
        tabS[e] = offL[lo] + (e - cnbL[lo]) * CHUNK;
    }
}

// Pass 3: scatter edges into relation-sorted arrays (LDS cursors only)
__global__ __launch_bounds__(256) void scatter_sorted(
    const int* __restrict__ src, const int* __restrict__ dst,
    const int* __restrict__ et, const float* __restrict__ en,
    const int* __restrict__ offs, const int* __restrict__ blockPrefix,
    int* __restrict__ srcS, int* __restrict__ dstS, float* __restrict__ normS)
{
    __shared__ int lcur[NR];
    for (int i = threadIdx.x; i < NR; i += 256)
        lcur[i] = offs[i] + blockPrefix[blockIdx.x * NR + i];
    __syncthreads();
#pragma unroll
    for (int i = 0; i < EPB / 256; ++i) {
        int e = blockIdx.x * EPB + i * 256 + threadIdx.x;
        if (e < NE) {
            int r = et[e];
            int p = atomicAdd(&lcur[r], 1);
            srcS[p] = src[e]; dstS[p] = dst[e]; normS[p] = en[e];
        }
    }
}

// Edge kernel: one block per (relation, 64-edge chunk). W[r] staged in LDS
// once per block with XOR bank swizzle; 4-edge unroll shares each ds_read_b128
// across 4 edges' FMAs. x-row broadcast via v_readlane. Tail edges masked.
// NOTE: min-waves/EU kept at 4 -> 128-VGPR budget. (256,8) spilled: VGPR=32,
// FETCH 18MB->670MB scratch traffic, 6x regression (R6).
__global__ __launch_bounds__(256, 4) void edge_lds(
    const int* __restrict__ srcS, const int* __restrict__ dstS,
    const float* __restrict__ normS, const int* __restrict__ offs,
    const int* __restrict__ tabR, const int* __restrict__ tabS,
    const int* __restrict__ nbG, const float* __restrict__ x,
    const float* __restrict__ Wt, float* __restrict__ s)
{
    __shared__ f32x4 WL4[1024];                    // 16 KB
    int b = blockIdx.x;
    if (b >= nbG[0]) return;
    int r  = tabR[b];
    int cs = tabS[b];
    int tid = threadIdx.x;

    // stage Wt[r] (d-major rows) with slot swizzle: slot = g ^ (d&7)
    {
        const f32x4* __restrict__ Wg = (const f32x4*)(Wt + (size_t)r * 4096);
#pragma unroll
        for (int i = 0; i < 4; ++i) {
            int idx = tid + i * 256;               // f32x4 index 0..1023
            f32x4 v = Wg[idx];
            int d = idx >> 4, g = idx & 15;
            *(f32x4*)((char*)WL4 + ((d << 8) | ((g ^ (d & 7)) << 4))) = v;
        }
    }
    __syncthreads();

    int wid  = tid >> 6;
    int lane = tid & 63;
    int wstart = cs + wid * 16;
    int wend   = cs + CHUNK;
    int segE   = offs[r + 1];
    if (segE < wend) wend = segE;
    int cw = wend - wstart;
    if (cw <= 0) return;
    if (cw > 16) cw = 16;

    int ei   = wstart + (lane < cw ? lane : 0);    // lane i holds meta of edge wstart+i
    int srcv = srcS[ei];
    int dstv = dstS[ei];
    int nrmv = __float_as_int(normS[ei]);

    const int base = (lane << 8) | ((lane & 7) << 4);

    float xv0 = x[(size_t)__builtin_amdgcn_readlane(srcv, 0) * 64 + lane];
    float xv1 = x[(size_t)__builtin_amdgcn_readlane(srcv, 1) * 64 + lane];
    float xv2 = x[(size_t)__builtin_amdgcn_readlane(srcv, 2) * 64 + lane];
    float xv3 = x[(size_t)__builtin_amdgcn_readlane(srcv, 3) * 64 + lane];

    for (int g0 = 0; g0 < cw; g0 += 4) {
        int xc[4];
        xc[0] = __float_as_int(xv0); xc[1] = __float_as_int(xv1);
        xc[2] = __float_as_int(xv2); xc[3] = __float_as_int(xv3);
        int dn[4]; float nm[4];
#pragma unroll
        for (int j = 0; j < 4; ++j) {
            dn[j] = __builtin_amdgcn_readlane(dstv, g0 + j);
            nm[j] = __int_as_float(__builtin_amdgcn_readlane(nrmv, g0 + j));
        }
        if (g0 + 4 < cw) {
            xv0 = x[(size_t)__builtin_amdgcn_readlane(srcv, g0 + 4) * 64 + lane];
            xv1 = x[(size_t)__builtin_amdgcn_readlane(srcv, g0 + 5) * 64 + lane];
            xv2 = x[(size_t)__builtin_amdgcn_readlane(srcv, g0 + 6) * 64 + lane];
            xv3 = x[(size_t)__builtin_amdgcn_readlane(srcv, g0 + 7) * 64 + lane];
        }
        float a[4][4] = {{0.f}};
#pragma unroll
        for (int t = 0; t < 16; ++t) {
            f32x4 ww = *(const f32x4*)((const char*)WL4 + (base ^ (t << 4)));
#pragma unroll
            for (int j = 0; j < 4; ++j) {
                a[j][0] = fmaf(__int_as_float(__builtin_amdgcn_readlane(xc[j], 4 * t + 0)), ww.x, a[j][0]);
                a[j][1] = fmaf(__int_as_float(__builtin_amdgcn_readlane(xc[j], 4 * t + 1)), ww.y, a[j][1]);
                a[j][2] = fmaf(__int_as_float(__builtin_amdgcn_readlane(xc[j], 4 * t + 2)), ww.z, a[j][2]);
                a[j][3] = fmaf(__int_as_float(__builtin_amdgcn_readlane(xc[j], 4 * t + 3)), ww.w, a[j][3]);
            }
        }
#pragma unroll
        for (int j = 0; j < 4; ++j)
            if (g0 + j < cw)
                atomicAdd(&s[(size_t)dn[j] * 64 + lane],
                          ((a[j][0] + a[j][1]) + (a[j][2] + a[j][3])) * nm[j]);
    }
}

// Node kernel: rT staged in LDS (same swizzle), 8 nodes/wave (2 groups of 4).
// NN % 8 == 0 so active waves have full groups. In-place-safe (x == out).
__global__ __launch_bounds__(256, 4) void node_lds(
    const float* __restrict__ x, float* __restrict__ s,
    const float* __restrict__ cnt, const float* __restrict__ rT,
    const float* __restrict__ bias, float* __restrict__ out, int zero_s)
{
    __shared__ f32x4 RL4[1024];                    // 16 KB
    int tid = threadIdx.x;
    {
        const f32x4* __restrict__ Rg = (const f32x4*)rT;
#pragma unroll
        for (int i = 0; i < 4; ++i) {
            int idx = tid + i * 256;
            f32x4 v = Rg[idx];
            int d = idx >> 4, g = idx & 15;
            *(f32x4*)((char*)RL4 + ((d << 8) | ((g ^ (d & 7)) << 4))) = v;
        }
    }
    __syncthreads();

    int wid  = tid >> 6;
    int lane = tid & 63;
    int n0 = blockIdx.x * NPB + wid * 8;
    if (n0 >= NN) return;

    const int base = (lane << 8) | ((lane & 7) << 4);
    float bv = bias[lane];

#pragma unroll
    for (int gq = 0; gq < 2; ++gq) {
        int n = n0 + gq * 4;
        int xc[4]; float sv[4], cv[4];
#pragma unroll
        for (int j = 0; j < 4; ++j) {
            xc[j] = __float_as_int(x[(size_t)(n + j) * 64 + lane]);
            sv[j] = s[(size_t)(n + j) * 64 + lane];
            cv[j] = cnt[n + j];
        }
        float a[4][4] = {{0.f}};
#pragma unroll
        for (int t = 0; t < 16; ++t) {
            f32x4 ww = *(const f32x4*)((const char*)RL4 + (base ^ (t << 4)));
#pragma unroll
            for (int j = 0; j < 4; ++j) {
                a[j][0] = fmaf(__int_as_float(__builtin_amdgcn_readlane(xc[j], 4 * t + 0)), ww.x, a[j][0]);
                a[j][1] = fmaf(__int_as_float(__builtin_amdgcn_readlane(xc[j], 4 * t + 1)), ww.y, a[j][1]);
                a[j][2] = fmaf(__int_as_float(__builtin_amdgcn_readlane(xc[j], 4 * t + 2)), ww.z, a[j][2]);
                a[j][3] = fmaf(__int_as_float(__builtin_amdgcn_readlane(xc[j], 4 * t + 3)), ww.w, a[j][3]);
            }
        }
#pragma unroll
        for (int j = 0; j < 4; ++j) {
            float c = cv[j] > 1.f ? cv[j] : 1.f;
            out[(size_t)(n + j) * 64 + lane] =
                sv[j] / c + ((a[j][0] + a[j][1]) + (a[j][2] + a[j][3])) + bv;
            if (zero_s) s[(size_t)(n + j) * 64 + lane] = 0.f;
        }
    }
}

extern "C" void kernel_launch(void* const* d_in, const int* in_sizes, int n_in,
                              void* d_out, int out_size, void* d_ws, size_t ws_size,
                              hipStream_t stream) {
    const int*   entity    = (const int*)d_in[0];
    const int*   edge_index= (const int*)d_in[1];    // [2, NE]
    const int*   edge_type = (const int*)d_in[2];
    const float* edge_norm = (const float*)d_in[3];
    const float* emb       = (const float*)d_in[4];
    const float* basis1    = (const float*)d_in[5];
    const float* att1      = (const float*)d_in[6];
    const float* root1     = (const float*)d_in[7];
    const float* bias1     = (const float*)d_in[8];
    const float* basis2    = (const float*)d_in[9];
    const float* att2      = (const float*)d_in[10];
    const float* root2     = (const float*)d_in[11];
    const float* bias2     = (const float*)d_in[12];

    const int* src = edge_index;
    const int* dst = edge_index + NE;

    // float arrays first (16B alignment for f32x4 loads), ints at the end
    float* ws    = (float*)d_ws;
    float* Wt1   = ws;                           // NR*4096
    float* Wt2   = Wt1 + (size_t)NR * 4096;      // NR*4096
    float* rT1   = Wt2 + (size_t)NR * 4096;      // 4096
    float* rT2   = rT1 + 4096;                   // 4096
    float* x0    = rT2 + 4096;                   // NN*D
    float* s     = x0  + (size_t)NN * D;         // NN*D
    float* cnt   = s   + (size_t)NN * D;         // NN
    float* normS = cnt + NN;                     // NE
    int*   offs        = (int*)(normS + NE);     // NR+1 (+pad)
    int*   relTot      = offs + NR + 3;          // NR
    int*   nbG         = relTot + NR;            // 1 (+pad)
    int*   blockHist   = nbG + 3;                // HB*NR
    int*   blockPrefix = blockHist + HB * NR;    // HB*NR
    int*   tabR        = blockPrefix + HB * NR;  // EGRID
    int*   tabS        = tabR + EGRID;           // EGRID
    int*   srcS        = tabS + EGRID;           // NE
    int*   dstS        = srcS + NE;              // NE

    float* out = (float*)d_out;

    // zero s + cnt (contiguous)
    hipMemsetAsync(s, 0, ((size_t)NN * D + NN) * sizeof(float), stream);

    compute_wt<<<2 * NR + 2, 256, 0, stream>>>(att1, basis1, root1,
                                               att2, basis2, root2,
                                               Wt1, Wt2, rT1, rT2);
    gather_emb<<<(NN * 16 + 255) / 256, 256, 0, stream>>>(
        entity, (const f32x4*)emb, (f32x4*)x0);
    hist_edges<<<HB, 256, 0, stream>>>(edge_type, dst, blockHist, cnt);
    colscan<<<NR, 256, 0, stream>>>(blockHist, blockPrefix, relTot);
    scanK<<<1, 256, 0, stream>>>(relTot, offs, nbG, tabR, tabS);
    scatter_sorted<<<HB, 256, 0, stream>>>(src, dst, edge_type, edge_norm,
                                           offs, blockPrefix, srcS, dstS, normS);

    // ---- layer 1 ----
    edge_lds<<<EGRID, 256, 0, stream>>>(srcS, dstS, normS, offs,
                                        tabR, tabS, nbG, x0, Wt1, s);
    node_lds<<<NGRID, 256, 0, stream>>>(x0, s, cnt, rT1, bias1, out, 1);

    // ---- layer 2 ----
    edge_lds<<<EGRID, 256, 0, stream>>>(srcS, dstS, normS, offs,
                                        tabR, tabS, nbG, out, Wt2, s);
    node_lds<<<NGRID, 256, 0, stream>>>(out, s, cnt, rT2, bias2, out, 0);
}

// Round 8
// 145.871 us; speedup vs baseline: 5.6182x; 1.3096x over previous
//
#include <hip/hip_runtime.h>

#define NN 50000      // N_ENT
#define NR 100        // N_REL2
#define NB 16         // N_BASES
#define D  64         // DIM
#define NE 100000     // N_EDGES

#define HB  196       // histogram/scatter blocks
#define EPB 512       // edges per block in hist/scatter

#define CHUNK 256     // edges per edge block (4 waves x 4 groups x 16)
#define EGRID 512     // >= sum ceil(len_r/256) <= 391+100

#define NPB 256       // nodes per node block (4 waves x 4 groups x 16)
#define NGRID ((NN + NPB - 1) / NPB)

typedef float f32x4  __attribute__((ext_vector_type(4)));
typedef short bf16x8 __attribute__((ext_vector_type(8)));   // 8 bf16 = 4 VGPRs

__device__ __forceinline__ short f2bf(float f) {            // fp32 -> bf16 RNE
    unsigned u = __float_as_uint(f);
    return (short)((u + 0x7FFFu + ((u >> 16) & 1u)) >> 16);
}

__device__ __forceinline__ bf16x8 pack8(f32x4 a, f32x4 b) {
    bf16x8 t;
    t[0] = f2bf(a.x); t[1] = f2bf(a.y); t[2] = f2bf(a.z); t[3] = f2bf(a.w);
    t[4] = f2bf(b.x); t[5] = f2bf(b.y); t[6] = f2bf(b.z); t[7] = f2bf(b.w);
    return t;
}

// Fused weight prep. Blocks 0..199: Wt[layer][r][d][k] = sum_b att[r,b]*basis[b,k,d]
// (transposed via padded-LDS). Blocks 200..201: rT[d][k] = root[k][d].
__global__ __launch_bounds__(256) void compute_wt(
    const float* __restrict__ att1, const float* __restrict__ basis1,
    const float* __restrict__ root1,
    const float* __restrict__ att2, const float* __restrict__ basis2,
    const float* __restrict__ root2,
    float* __restrict__ Wt1, float* __restrict__ Wt2,
    float* __restrict__ rT1, float* __restrict__ rT2)
{
    __shared__ float t[64 * 65];
    int b = blockIdx.x;
    if (b < 2 * NR) {
        int layer = b >= NR;
        int r = layer ? b - NR : b;
        const float* att   = layer ? att2 : att1;
        const float* basis = layer ? basis2 : basis1;
        float*       Wt    = layer ? Wt2 : Wt1;
        float a[NB];
#pragma unroll
        for (int bb = 0; bb < NB; ++bb) a[bb] = att[r * NB + bb];
#pragma unroll
        for (int i = 0; i < 16; ++i) {
            int idx = i * 256 + threadIdx.x;        // [k][d] linear
            float acc = 0.f;
#pragma unroll
            for (int bb = 0; bb < NB; ++bb) acc += a[bb] * basis[bb * 4096 + idx];
            t[(idx >> 6) * 65 + (idx & 63)] = acc;  // t[k][d], padded
        }
        __syncthreads();
#pragma unroll
        for (int i = 0; i < 16; ++i) {
            int j = i * 256 + threadIdx.x;          // [d][k] linear
            Wt[(size_t)r * 4096 + j] = t[(j & 63) * 65 + (j >> 6)];
        }
    } else {
        const float* root = (b == 2 * NR) ? root1 : root2;
        float*       rT   = (b == 2 * NR) ? rT1 : rT2;
#pragma unroll
        for (int i = 0; i < 16; ++i) {
            int idx = i * 256 + threadIdx.x;
            t[(idx >> 6) * 65 + (idx & 63)] = root[idx];
        }
        __syncthreads();
#pragma unroll
        for (int i = 0; i < 16; ++i) {
            int j = i * 256 + threadIdx.x;
            rT[j] = t[(j & 63) * 65 + (j >> 6)];
        }
    }
}

// x0[n, :] = emb[entity[n], :]  (float4 vectorized)
__global__ __launch_bounds__(256) void gather_emb(
    const int* __restrict__ entity, const f32x4* __restrict__ emb4,
    f32x4* __restrict__ x04)
{
    int idx = blockIdx.x * 256 + threadIdx.x;      // over NN*16
    if (idx >= NN * 16) return;
    int n = idx >> 4;
    int q = idx & 15;
    x04[idx] = emb4[(size_t)entity[n] * 16 + q];
}

// Pass 1: per-block relation histogram (LDS atomics) + node in-degree
__global__ __launch_bounds__(256) void hist_edges(
    const int* __restrict__ et, const int* __restrict__ dst,
    int* __restrict__ blockHist, float* __restrict__ cnt)
{
    __shared__ int lh[NR];
    for (int i = threadIdx.x; i < NR; i += 256) lh[i] = 0;
    __syncthreads();
#pragma unroll
    for (int i = 0; i < EPB / 256; ++i) {
        int e = blockIdx.x * EPB + i * 256 + threadIdx.x;
        if (e < NE) {
            atomicAdd(&lh[et[e]], 1);
            atomicAdd(&cnt[dst[e]], 1.0f);
        }
    }
    __syncthreads();
    for (int i = threadIdx.x; i < NR; i += 256)
        blockHist[blockIdx.x * NR + i] = lh[i];
}

// Pass 2a: per-relation column scan over the 196 block histograms.
__global__ __launch_bounds__(256) void colscan(
    const int* __restrict__ blockHist, int* __restrict__ blockPrefix,
    int* __restrict__ relTot)
{
    __shared__ int sc[256];
    int r = blockIdx.x;
    int t = threadIdx.x;
    int v = (t < HB) ? blockHist[t * NR + r] : 0;
    sc[t] = v;
    __syncthreads();
#pragma unroll
    for (int off = 1; off < 256; off <<= 1) {
        int a = (t >= off) ? sc[t - off] : 0;
        __syncthreads();
        sc[t] += a;
        __syncthreads();
    }
    if (t < HB) blockPrefix[t * NR + r] = sc[t] - v;   // exclusive
    if (t == 0) relTot[r] = sc[255];
}

// Pass 2b: tiny single-block: relation offsets, chunk-count prefix, chunk table.
__global__ __launch_bounds__(256) void scanK(
    const int* __restrict__ relTot, int* __restrict__ offs,
    int* __restrict__ nbG, int* __restrict__ tabR, int* __restrict__ tabS)
{
    __shared__ int totL[NR];
    __shared__ int offL[NR + 1];
    __shared__ int cnbL[NR + 1];
    int t = threadIdx.x;
    if (t < NR) totL[t] = relTot[t];
    __syncthreads();
    if (t == 0) {
        int off = 0, cb = 0;
        for (int r = 0; r < NR; ++r) {
            offL[r] = off; cnbL[r] = cb;
            off += totL[r];
            cb  += (totL[r] + CHUNK - 1) / CHUNK;
        }
        offL[NR] = off; cnbL[NR] = cb;
    }
    __syncthreads();
    if (t <= NR) offs[t] = offL[t];
    if (t == 0) nbG[0] = cnbL[NR];
    int nb = cnbL[NR];
    for (int e = t; e < nb; e += 256) {
        int lo = 0, hi = NR;                      // find r: cnbL[r] <= e < cnbL[r+1]
        while (hi - lo > 1) { int mid = (lo + hi) >> 1; if (cnbL[mid] <= e) lo = mid; else hi = mid; }
        tabR[e] = lo;
        tabS[e] = offL[lo] + (e - cnbL[lo]) * CHUNK;
    }
}

// Pass 3: scatter edges into relation-sorted arrays (LDS cursors only)
__global__ __launch_bounds__(256) void scatter_sorted(
    const int* __restrict__ src, const int* __restrict__ dst,
    const int* __restrict__ et, const float* __restrict__ en,
    const int* __restrict__ offs, const int* __restrict__ blockPrefix,
    int* __restrict__ srcS, int* __restrict__ dstS, float* __restrict__ normS)
{
    __shared__ int lcur[NR];
    for (int i = threadIdx.x; i < NR; i += 256)
        lcur[i] = offs[i] + blockPrefix[blockIdx.x * NR + i];
    __syncthreads();
#pragma unroll
    for (int i = 0; i < EPB / 256; ++i) {
        int e = blockIdx.x * EPB + i * 256 + threadIdx.x;
        if (e < NE) {
            int r = et[e];
            int p = atomicAdd(&lcur[r], 1);
            srcS[p] = src[e]; dstS[p] = dst[e]; normS[p] = en[e];
        }
    }
}

// MFMA edge kernel. Block = (relation, 256-edge chunk); wave = 16 edges/group,
// 4 groups. W[r] staged fp32 in LDS ([64][68] pad), B-frags (bf16) built once
// per wave; per group: gather x rows pre-scaled by norm -> A-frags -> 8 MFMAs
// -> predicated row atomics. Fragment maps per cdna4_isa sec.10 / m89.
__global__ __launch_bounds__(256, 4) void edge_mfma(
    const int* __restrict__ srcS, const int* __restrict__ dstS,
    const float* __restrict__ normS, const int* __restrict__ offs,
    const int* __restrict__ tabR, const int* __restrict__ tabS,
    const int* __restrict__ nbG, const float* __restrict__ x,
    const float* __restrict__ Wt, float* __restrict__ s)
{
    __shared__ float LW[64 * 68];                  // LW[d][k], 17 KB
    int b = blockIdx.x;
    if (b >= nbG[0]) return;
    int r  = tabR[b];
    int cs = tabS[b];
    int tid = threadIdx.x;

    {
        const f32x4* __restrict__ Wg = (const f32x4*)(Wt + (size_t)r * 4096);
#pragma unroll
        for (int i = 0; i < 4; ++i) {
            int v = tid + i * 256;                 // vec4 idx 0..1023
            int d = v >> 4, k4 = v & 15;
            *(f32x4*)(LW + d * 68 + k4 * 4) = Wg[v];
        }
    }
    __syncthreads();

    int lane = tid & 63, wid = tid >> 6;
    int c15 = lane & 15, kg = lane >> 4;           // col / k-group

    // B[k][col] = W[k][col] = LW[col][k]; frag k = ks*32 + kg*8 + j
    bf16x8 B[4][2];
#pragma unroll
    for (int nt = 0; nt < 4; ++nt)
#pragma unroll
        for (int ks = 0; ks < 2; ++ks) {
            const f32x4* p = (const f32x4*)(LW + (nt * 16 + c15) * 68 + ks * 32 + kg * 8);
            B[nt][ks] = pack8(p[0], p[1]);
        }

    int segE = offs[r + 1];
    int bend = cs + CHUNK < segE ? cs + CHUNK : segE;

#pragma unroll 1
    for (int g = 0; g < 4; ++g) {
        int gs = cs + wid * 64 + g * 16;           // wave-uniform
        if (gs >= bend) break;
        int ge = gs + 16 < bend ? gs + 16 : bend;

        int e  = gs + c15;                         // A row = c15
        int ec = e < ge ? e : ge - 1;
        float nrm = (e < ge) ? normS[ec] : 0.f;    // zero-pad tail rows
        int   sn  = srcS[ec];

        const f32x4* xr  = (const f32x4*)(x + (size_t)sn * 64 + kg * 8);
        const f32x4* xr2 = (const f32x4*)(x + (size_t)sn * 64 + 32 + kg * 8);
        bf16x8 A0 = pack8(xr[0]  * nrm, xr[1]  * nrm);   // k-step 0
        bf16x8 A1 = pack8(xr2[0] * nrm, xr2[1] * nrm);   // k-step 1

        f32x4 z = {0.f, 0.f, 0.f, 0.f};
        f32x4 acc[4] = {z, z, z, z};
#pragma unroll
        for (int nt = 0; nt < 4; ++nt) {
            acc[nt] = __builtin_amdgcn_mfma_f32_16x16x32_bf16(A0, B[nt][0], acc[nt], 0, 0, 0);
            acc[nt] = __builtin_amdgcn_mfma_f32_16x16x32_bf16(A1, B[nt][1], acc[nt], 0, 0, 0);
        }

        int dn[4];                                 // C row = kg*4 + j
#pragma unroll
        for (int j = 0; j < 4; ++j) {
            int er = gs + kg * 4 + j;
            dn[j] = (er < ge) ? dstS[er] : -1;
        }
#pragma unroll
        for (int nt = 0; nt < 4; ++nt)
#pragma unroll
            for (int j = 0; j < 4; ++j)
                if (dn[j] >= 0)
                    atomicAdd(&s[(size_t)dn[j] * 64 + nt * 16 + c15], acc[nt][j]);
    }
}

// MFMA node kernel: out = s/max(cnt,1) + x@root + bias. Same structure, rows
// sequential (no gather/atomics). In-place-safe: wave reads its rows in
// A-build before writing them; waves own disjoint row ranges.
__global__ __launch_bounds__(256, 4) void node_mfma(
    const float* __restrict__ x, float* __restrict__ s,
    const float* __restrict__ cnt, const float* __restrict__ rT,
    const float* __restrict__ bias, float* __restrict__ out, int zero_s)
{
    __shared__ float LW[64 * 68];
    int tid = threadIdx.x;
    {
        const f32x4* __restrict__ Rg = (const f32x4*)rT;
#pragma unroll
        for (int i = 0; i < 4; ++i) {
            int v = tid + i * 256;
            int d = v >> 4, k4 = v & 15;
            *(f32x4*)(LW + d * 68 + k4 * 4) = Rg[v];
        }
    }
    __syncthreads();

    int lane = tid & 63, wid = tid >> 6;
    int c15 = lane & 15, kg = lane >> 4;

    bf16x8 B[4][2];
#pragma unroll
    for (int nt = 0; nt < 4; ++nt)
#pragma unroll
        for (int ks = 0; ks < 2; ++ks) {
            const f32x4* p = (const f32x4*)(LW + (nt * 16 + c15) * 68 + ks * 32 + kg * 8);
            B[nt][ks] = pack8(p[0], p[1]);
        }
    float bv[4];
#pragma unroll
    for (int nt = 0; nt < 4; ++nt) bv[nt] = bias[nt * 16 + c15];

#pragma unroll 1
    for (int g = 0; g < 4; ++g) {
        int gs = blockIdx.x * NPB + wid * 64 + g * 16;
        if (gs >= NN) break;
        int ge = gs + 16 < NN ? gs + 16 : NN;

        int n  = gs + c15;
        int nc = n < ge ? n : ge - 1;
        const f32x4* xr  = (const f32x4*)(x + (size_t)nc * 64 + kg * 8);
        const f32x4* xr2 = (const f32x4*)(x + (size_t)nc * 64 + 32 + kg * 8);
        bf16x8 A0 = pack8(xr[0], xr[1]);
        bf16x8 A1 = pack8(xr2[0], xr2[1]);

        f32x4 z = {0.f, 0.f, 0.f, 0.f};
        f32x4 acc[4] = {z, z, z, z};
#pragma unroll
        for (int nt = 0; nt < 4; ++nt) {
            acc[nt] = __builtin_amdgcn_mfma_f32_16x16x32_bf16(A0, B[nt][0], acc[nt], 0, 0, 0);
            acc[nt] = __builtin_amdgcn_mfma_f32_16x16x32_bf16(A1, B[nt][1], acc[nt], 0, 0, 0);
        }

        float cv[4];
#pragma unroll
        for (int j = 0; j < 4; ++j) {
            int nr = gs + kg * 4 + j;
            cv[j] = (nr < ge) ? cnt[nr] : 1.f;
        }
#pragma unroll
        for (int nt = 0; nt < 4; ++nt)
#pragma unroll
            for (int j = 0; j < 4; ++j) {
                int nr = gs + kg * 4 + j;
                if (nr < ge) {
                    size_t off = (size_t)nr * 64 + nt * 16 + c15;
                    float c = cv[j] > 1.f ? cv[j] : 1.f;
                    out[off] = s[off] / c + acc[nt][j] + bv[nt];
                    if (zero_s) s[off] = 0.f;
                }
            }
    }
}

extern "C" void kernel_launch(void* const* d_in, const int* in_sizes, int n_in,
                              void* d_out, int out_size, void* d_ws, size_t ws_size,
                              hipStream_t stream) {
    const int*   entity    = (const int*)d_in[0];
    const int*   edge_index= (const int*)d_in[1];    // [2, NE]
    const int*   edge_type = (const int*)d_in[2];
    const float* edge_norm = (const float*)d_in[3];
    const float* emb       = (const float*)d_in[4];
    const float* basis1    = (const float*)d_in[5];
    const float* att1      = (const float*)d_in[6];
    const float* root1     = (const float*)d_in[7];
    const float* bias1     = (const float*)d_in[8];
    const float* basis2    = (const float*)d_in[9];
    const float* att2      = (const float*)d_in[10];
    const float* root2     = (const float*)d_in[11];
    const float* bias2     = (const float*)d_in[12];

    const int* src = edge_index;
    const int* dst = edge_index + NE;

    // float arrays first (16B alignment for f32x4 loads), ints at the end
    float* ws    = (float*)d_ws;
    float* Wt1   = ws;                           // NR*4096
    float* Wt2   = Wt1 + (size_t)NR * 4096;      // NR*4096
    float* rT1   = Wt2 + (size_t)NR * 4096;      // 4096
    float* rT2   = rT1 + 4096;                   // 4096
    float* x0    = rT2 + 4096;                   // NN*D
    float* s     = x0  + (size_t)NN * D;         // NN*D
    float* cnt   = s   + (size_t)NN * D;         // NN
    float* normS = cnt + NN;                     // NE
    int*   offs        = (int*)(normS + NE);     // NR+1 (+pad)
    int*   relTot      = offs + NR + 3;          // NR
    int*   nbG         = relTot + NR;            // 1 (+pad)
    int*   blockHist   = nbG + 3;                // HB*NR
    int*   blockPrefix = blockHist + HB * NR;    // HB*NR
    int*   tabR        = blockPrefix + HB * NR;  // EGRID
    int*   tabS        = tabR + EGRID;           // EGRID
    int*   srcS        = tabS + EGRID;           // NE
    int*   dstS        = srcS + NE;              // NE

    float* out = (float*)d_out;

    // zero s + cnt (contiguous)
    hipMemsetAsync(s, 0, ((size_t)NN * D + NN) * sizeof(float), stream);

    compute_wt<<<2 * NR + 2, 256, 0, stream>>>(att1, basis1, root1,
                                               att2, basis2, root2,
                                               Wt1, Wt2, rT1, rT2);
    gather_emb<<<(NN * 16 + 255) / 256, 256, 0, stream>>>(
        entity, (const f32x4*)emb, (f32x4*)x0);
    hist_edges<<<HB, 256, 0, stream>>>(edge_type, dst, blockHist, cnt);
    colscan<<<NR, 256, 0, stream>>>(blockHist, blockPrefix, relTot);
    scanK<<<1, 256, 0, stream>>>(relTot, offs, nbG, tabR, tabS);
    scatter_sorted<<<HB, 256, 0, stream>>>(src, dst, edge_type, edge_norm,
                                           offs, blockPrefix, srcS, dstS, normS);

    // ---- layer 1 ----
    edge_mfma<<<EGRID, 256, 0, stream>>>(srcS, dstS, normS, offs,
                                         tabR, tabS, nbG, x0, Wt1, s);
    node_mfma<<<NGRID, 256, 0, stream>>>(x0, s, cnt, rT1, bias1, out, 1);

    // ---- layer 2 ----
    edge_mfma<<<EGRID, 256, 0, stream>>>(srcS, dstS, normS, offs,
                                         tabR, tabS, nbG, out, Wt2, s);
    node_mfma<<<NGRID, 256, 0, stream>>>(out, s, cnt, rT2, bias2, out, 0);
}

// Round 9
// 127.577 us; speedup vs baseline: 6.4238x; 1.1434x over previous
//
#include <hip/hip_runtime.h>

#define NN 50000      // N_ENT
#define NR 100        // N_REL2
#define NB 16         // N_BASES
#define D  64         // DIM
#define NE 100000     // N_EDGES

#define HB  196       // histogram/scatter blocks
#define EPB 512       // edges per block in hist/scatter

#define CHUNK 128     // edges per edge block (4 waves x 2 groups x 16)
#define GROUPS 2
#define EGRID 1024    // >= sum ceil(len_r/128) <= 782+100

#define NPB 128       // nodes per node block (4 waves x 2 groups x 16)
#define NGRID ((NN + NPB - 1) / NPB)

typedef float f32x4  __attribute__((ext_vector_type(4)));
typedef short bf16x8 __attribute__((ext_vector_type(8)));   // 8 bf16 = 4 VGPRs

__device__ __forceinline__ short f2bf(float f) {            // fp32 -> bf16 RNE
    unsigned u = __float_as_uint(f);
    return (short)((u + 0x7FFFu + ((u >> 16) & 1u)) >> 16);
}

__device__ __forceinline__ bf16x8 pack8(f32x4 a, f32x4 b) {
    bf16x8 t;
    t[0] = f2bf(a.x); t[1] = f2bf(a.y); t[2] = f2bf(a.z); t[3] = f2bf(a.w);
    t[4] = f2bf(b.x); t[5] = f2bf(b.y); t[6] = f2bf(b.z); t[7] = f2bf(b.w);
    return t;
}

// Fused weight prep. Blocks 0..199: Wt[layer][r][d][k] = sum_b att[r,b]*basis[b,k,d]
// (transposed via padded-LDS). Blocks 200..201: rT[d][k] = root[k][d].
__global__ __launch_bounds__(256) void compute_wt(
    const float* __restrict__ att1, const float* __restrict__ basis1,
    const float* __restrict__ root1,
    const float* __restrict__ att2, const float* __restrict__ basis2,
    const float* __restrict__ root2,
    float* __restrict__ Wt1, float* __restrict__ Wt2,
    float* __restrict__ rT1, float* __restrict__ rT2)
{
    __shared__ float t[64 * 65];
    int b = blockIdx.x;
    if (b < 2 * NR) {
        int layer = b >= NR;
        int r = layer ? b - NR : b;
        const float* att   = layer ? att2 : att1;
        const float* basis = layer ? basis2 : basis1;
        float*       Wt    = layer ? Wt2 : Wt1;
        float a[NB];
#pragma unroll
        for (int bb = 0; bb < NB; ++bb) a[bb] = att[r * NB + bb];
#pragma unroll
        for (int i = 0; i < 16; ++i) {
            int idx = i * 256 + threadIdx.x;        // [k][d] linear
            float acc = 0.f;
#pragma unroll
            for (int bb = 0; bb < NB; ++bb) acc += a[bb] * basis[bb * 4096 + idx];
            t[(idx >> 6) * 65 + (idx & 63)] = acc;  // t[k][d], padded
        }
        __syncthreads();
#pragma unroll
        for (int i = 0; i < 16; ++i) {
            int j = i * 256 + threadIdx.x;          // [d][k] linear
            Wt[(size_t)r * 4096 + j] = t[(j & 63) * 65 + (j >> 6)];
        }
    } else {
        const float* root = (b == 2 * NR) ? root1 : root2;
        float*       rT   = (b == 2 * NR) ? rT1 : rT2;
#pragma unroll
        for (int i = 0; i < 16; ++i) {
            int idx = i * 256 + threadIdx.x;
            t[(idx >> 6) * 65 + (idx & 63)] = root[idx];
        }
        __syncthreads();
#pragma unroll
        for (int i = 0; i < 16; ++i) {
            int j = i * 256 + threadIdx.x;
            rT[j] = t[(j & 63) * 65 + (j >> 6)];
        }
    }
}

// x0[n, :] = emb[entity[n], :]  (float4) + zero s (same index space) + zero cnt.
// Replaces hipMemsetAsync: runtime fill kernel measured 41 us at 313 GB/s (R8).
__global__ __launch_bounds__(256) void gather_zero(
    const int* __restrict__ entity, const f32x4* __restrict__ emb4,
    f32x4* __restrict__ x04, f32x4* __restrict__ s4, f32x4* __restrict__ cnt4)
{
    int idx = blockIdx.x * 256 + threadIdx.x;      // over NN*16
    if (idx >= NN * 16) return;
    int n = idx >> 4;
    int q = idx & 15;
    f32x4 z = {0.f, 0.f, 0.f, 0.f};
    x04[idx] = emb4[(size_t)entity[n] * 16 + q];
    s4[idx] = z;
    if (idx < NN / 4) cnt4[idx] = z;
}

// Pass 1: per-block relation histogram (LDS atomics) + node in-degree
__global__ __launch_bounds__(256) void hist_edges(
    const int* __restrict__ et, const int* __restrict__ dst,
    int* __restrict__ blockHist, float* __restrict__ cnt)
{
    __shared__ int lh[NR];
    for (int i = threadIdx.x; i < NR; i += 256) lh[i] = 0;
    __syncthreads();
#pragma unroll
    for (int i = 0; i < EPB / 256; ++i) {
        int e = blockIdx.x * EPB + i * 256 + threadIdx.x;
        if (e < NE) {
            atomicAdd(&lh[et[e]], 1);
            atomicAdd(&cnt[dst[e]], 1.0f);
        }
    }
    __syncthreads();
    for (int i = threadIdx.x; i < NR; i += 256)
        blockHist[blockIdx.x * NR + i] = lh[i];
}

// Pass 2a: per-relation column scan over the 196 block histograms.
__global__ __launch_bounds__(256) void colscan(
    const int* __restrict__ blockHist, int* __restrict__ blockPrefix,
    int* __restrict__ relTot)
{
    __shared__ int sc[256];
    int r = blockIdx.x;
    int t = threadIdx.x;
    int v = (t < HB) ? blockHist[t * NR + r] : 0;
    sc[t] = v;
    __syncthreads();
#pragma unroll
    for (int off = 1; off < 256; off <<= 1) {
        int a = (t >= off) ? sc[t - off] : 0;
        __syncthreads();
        sc[t] += a;
        __syncthreads();
    }
    if (t < HB) blockPrefix[t * NR + r] = sc[t] - v;   // exclusive
    if (t == 0) relTot[r] = sc[255];
}

// Pass 2b: tiny single-block: relation offsets, chunk-count prefix, chunk table.
__global__ __launch_bounds__(256) void scanK(
    const int* __restrict__ relTot, int* __restrict__ offs,
    int* __restrict__ nbG, int* __restrict__ tabR, int* __restrict__ tabS)
{
    __shared__ int totL[NR];
    __shared__ int offL[NR + 1];
    __shared__ int cnbL[NR + 1];
    int t = threadIdx.x;
    if (t < NR) totL[t] = relTot[t];
    __syncthreads();
    if (t == 0) {
        int off = 0, cb = 0;
        for (int r = 0; r < NR; ++r) {
            offL[r] = off; cnbL[r] = cb;
            off += totL[r];
            cb  += (totL[r] + CHUNK - 1) / CHUNK;
        }
        offL[NR] = off; cnbL[NR] = cb;
    }
    __syncthreads();
    if (t <= NR) offs[t] = offL[t];
    if (t == 0) nbG[0] = cnbL[NR];
    int nb = cnbL[NR];
    for (int e = t; e < nb; e += 256) {
        int lo = 0, hi = NR;                      // find r: cnbL[r] <= e < cnbL[r+1]
        while (hi - lo > 1) { int mid = (lo + hi) >> 1; if (cnbL[mid] <= e) lo = mid; else hi = mid; }
        tabR[e] = lo;
        tabS[e] = offL[lo] + (e - cnbL[lo]) * CHUNK;
    }
}

// Pass 3: scatter edges into relation-sorted arrays (LDS cursors only)
__global__ __launch_bounds__(256) void scatter_sorted(
    const int* __restrict__ src, const int* __restrict__ dst,
    const int* __restrict__ et, const float* __restrict__ en,
    const int* __restrict__ offs, const int* __restrict__ blockPrefix,
    int* __restrict__ srcS, int* __restrict__ dstS, float* __restrict__ normS)
{
    __shared__ int lcur[NR];
    for (int i = threadIdx.x; i < NR; i += 256)
        lcur[i] = offs[i] + blockPrefix[blockIdx.x * NR + i];
    __syncthreads();
#pragma unroll
    for (int i = 0; i < EPB / 256; ++i) {
        int e = blockIdx.x * EPB + i * 256 + threadIdx.x;
        if (e < NE) {
            int r = et[e];
            int p = atomicAdd(&lcur[r], 1);
            srcS[p] = src[e]; dstS[p] = dst[e]; normS[p] = en[e];
        }
    }
}

// MFMA edge kernel. Block = (relation, 128-edge chunk); wave = 16 edges/group,
// 2 groups. W[r] staged fp32 in LDS ([64][68] pad), B-frags (bf16) built once
// per wave; per group: gather x rows pre-scaled by norm -> A-frags -> 8 MFMAs
// -> predicated row atomics. Fragment maps per cdna4_isa sec.10 / m89.
__global__ __launch_bounds__(256, 4) void edge_mfma(
    const int* __restrict__ srcS, const int* __restrict__ dstS,
    const float* __restrict__ normS, const int* __restrict__ offs,
    const int* __restrict__ tabR, const int* __restrict__ tabS,
    const int* __restrict__ nbG, const float* __restrict__ x,
    const float* __restrict__ Wt, float* __restrict__ s)
{
    __shared__ float LW[64 * 68];                  // LW[d][k], 17 KB
    int b = blockIdx.x;
    if (b >= nbG[0]) return;
    int r  = tabR[b];
    int cs = tabS[b];
    int tid = threadIdx.x;

    {
        const f32x4* __restrict__ Wg = (const f32x4*)(Wt + (size_t)r * 4096);
#pragma unroll
        for (int i = 0; i < 4; ++i) {
            int v = tid + i * 256;                 // vec4 idx 0..1023
            int d = v >> 4, k4 = v & 15;
            *(f32x4*)(LW + d * 68 + k4 * 4) = Wg[v];
        }
    }
    __syncthreads();

    int lane = tid & 63, wid = tid >> 6;
    int c15 = lane & 15, kg = lane >> 4;           // col / k-group

    // B[k][col] = W[k][col] = LW[col][k]; frag k = ks*32 + kg*8 + j
    bf16x8 B[4][2];
#pragma unroll
    for (int nt = 0; nt < 4; ++nt)
#pragma unroll
        for (int ks = 0; ks < 2; ++ks) {
            const f32x4* p = (const f32x4*)(LW + (nt * 16 + c15) * 68 + ks * 32 + kg * 8);
            B[nt][ks] = pack8(p[0], p[1]);
        }

    int segE = offs[r + 1];
    int bend = cs + CHUNK < segE ? cs + CHUNK : segE;

#pragma unroll 1
    for (int g = 0; g < GROUPS; ++g) {
        int gs = cs + wid * (GROUPS * 16) + g * 16;    // wave-uniform
        if (gs >= bend) break;
        int ge = gs + 16 < bend ? gs + 16 : bend;

        int e  = gs + c15;                         // A row = c15
        int ec = e < ge ? e : ge - 1;
        float nrm = (e < ge) ? normS[ec] : 0.f;    // zero-pad tail rows
        int   sn  = srcS[ec];

        const f32x4* xr  = (const f32x4*)(x + (size_t)sn * 64 + kg * 8);
        const f32x4* xr2 = (const f32x4*)(x + (size_t)sn * 64 + 32 + kg * 8);
        bf16x8 A0 = pack8(xr[0]  * nrm, xr[1]  * nrm);   // k-step 0
        bf16x8 A1 = pack8(xr2[0] * nrm, xr2[1] * nrm);   // k-step 1

        f32x4 z = {0.f, 0.f, 0.f, 0.f};
        f32x4 acc[4] = {z, z, z, z};
#pragma unroll
        for (int nt = 0; nt < 4; ++nt) {
            acc[nt] = __builtin_amdgcn_mfma_f32_16x16x32_bf16(A0, B[nt][0], acc[nt], 0, 0, 0);
            acc[nt] = __builtin_amdgcn_mfma_f32_16x16x32_bf16(A1, B[nt][1], acc[nt], 0, 0, 0);
        }

        int dn[4];                                 // C row = kg*4 + j
#pragma unroll
        for (int j = 0; j < 4; ++j) {
            int er = gs + kg * 4 + j;
            dn[j] = (er < ge) ? dstS[er] : -1;
        }
#pragma unroll
        for (int nt = 0; nt < 4; ++nt)
#pragma unroll
            for (int j = 0; j < 4; ++j)
                if (dn[j] >= 0)
                    atomicAdd(&s[(size_t)dn[j] * 64 + nt * 16 + c15], acc[nt][j]);
    }
}

// MFMA node kernel: out = s/max(cnt,1) + x@root + bias. Same structure, rows
// sequential (no gather/atomics). In-place-safe: wave reads its rows in
// A-build before writing them; waves own disjoint row ranges.
__global__ __launch_bounds__(256, 4) void node_mfma(
    const float* __restrict__ x, float* __restrict__ s,
    const float* __restrict__ cnt, const float* __restrict__ rT,
    const float* __restrict__ bias, float* __restrict__ out, int zero_s)
{
    __shared__ float LW[64 * 68];
    int tid = threadIdx.x;
    {
        const f32x4* __restrict__ Rg = (const f32x4*)rT;
#pragma unroll
        for (int i = 0; i < 4; ++i) {
            int v = tid + i * 256;
            int d = v >> 4, k4 = v & 15;
            *(f32x4*)(LW + d * 68 + k4 * 4) = Rg[v];
        }
    }
    __syncthreads();

    int lane = tid & 63, wid = tid >> 6;
    int c15 = lane & 15, kg = lane >> 4;

    bf16x8 B[4][2];
#pragma unroll
    for (int nt = 0; nt < 4; ++nt)
#pragma unroll
        for (int ks = 0; ks < 2; ++ks) {
            const f32x4* p = (const f32x4*)(LW + (nt * 16 + c15) * 68 + ks * 32 + kg * 8);
            B[nt][ks] = pack8(p[0], p[1]);
        }
    float bv[4];
#pragma unroll
    for (int nt = 0; nt < 4; ++nt) bv[nt] = bias[nt * 16 + c15];

#pragma unroll 1
    for (int g = 0; g < GROUPS; ++g) {
        int gs = blockIdx.x * NPB + wid * (GROUPS * 16) + g * 16;
        if (gs >= NN) break;
        int ge = gs + 16 < NN ? gs + 16 : NN;

        int n  = gs + c15;
        int nc = n < ge ? n : ge - 1;
        const f32x4* xr  = (const f32x4*)(x + (size_t)nc * 64 + kg * 8);
        const f32x4* xr2 = (const f32x4*)(x + (size_t)nc * 64 + 32 + kg * 8);
        bf16x8 A0 = pack8(xr[0], xr[1]);
        bf16x8 A1 = pack8(xr2[0], xr2[1]);

        f32x4 z = {0.f, 0.f, 0.f, 0.f};
        f32x4 acc[4] = {z, z, z, z};
#pragma unroll
        for (int nt = 0; nt < 4; ++nt) {
            acc[nt] = __builtin_amdgcn_mfma_f32_16x16x32_bf16(A0, B[nt][0], acc[nt], 0, 0, 0);
            acc[nt] = __builtin_amdgcn_mfma_f32_16x16x32_bf16(A1, B[nt][1], acc[nt], 0, 0, 0);
        }

        float cv[4];
#pragma unroll
        for (int j = 0; j < 4; ++j) {
            int nr = gs + kg * 4 + j;
            cv[j] = (nr < ge) ? cnt[nr] : 1.f;
        }
#pragma unroll
        for (int nt = 0; nt < 4; ++nt)
#pragma unroll
            for (int j = 0; j < 4; ++j) {
                int nr = gs + kg * 4 + j;
                if (nr < ge) {
                    size_t off = (size_t)nr * 64 + nt * 16 + c15;
                    float c = cv[j] > 1.f ? cv[j] : 1.f;
                    out[off] = s[off] / c + acc[nt][j] + bv[nt];
                    if (zero_s) s[off] = 0.f;
                }
            }
    }
}

extern "C" void kernel_launch(void* const* d_in, const int* in_sizes, int n_in,
                              void* d_out, int out_size, void* d_ws, size_t ws_size,
                              hipStream_t stream) {
    const int*   entity    = (const int*)d_in[0];
    const int*   edge_index= (const int*)d_in[1];    // [2, NE]
    const int*   edge_type = (const int*)d_in[2];
    const float* edge_norm = (const float*)d_in[3];
    const float* emb       = (const float*)d_in[4];
    const float* basis1    = (const float*)d_in[5];
    const float* att1      = (const float*)d_in[6];
    const float* root1     = (const float*)d_in[7];
    const float* bias1     = (const float*)d_in[8];
    const float* basis2    = (const float*)d_in[9];
    const float* att2      = (const float*)d_in[10];
    const float* root2     = (const float*)d_in[11];
    const float* bias2     = (const float*)d_in[12];

    const int* src = edge_index;
    const int* dst = edge_index + NE;

    // float arrays first (16B alignment for f32x4 loads), ints at the end
    float* ws    = (float*)d_ws;
    float* Wt1   = ws;                           // NR*4096
    float* Wt2   = Wt1 + (size_t)NR * 4096;      // NR*4096
    float* rT1   = Wt2 + (size_t)NR * 4096;      // 4096
    float* rT2   = rT1 + 4096;                   // 4096
    float* x0    = rT2 + 4096;                   // NN*D
    float* s     = x0  + (size_t)NN * D;         // NN*D
    float* cnt   = s   + (size_t)NN * D;         // NN
    float* normS = cnt + NN;                     // NE
    int*   offs        = (int*)(normS + NE);     // NR+1 (+pad)
    int*   relTot      = offs + NR + 3;          // NR
    int*   nbG         = relTot + NR;            // 1 (+pad)
    int*   blockHist   = nbG + 3;                // HB*NR
    int*   blockPrefix = blockHist + HB * NR;    // HB*NR
    int*   tabR        = blockPrefix + HB * NR;  // EGRID
    int*   tabS        = tabR + EGRID;           // EGRID
    int*   srcS        = tabS + EGRID;           // NE
    int*   dstS        = srcS + NE;              // NE

    float* out = (float*)d_out;

    compute_wt<<<2 * NR + 2, 256, 0, stream>>>(att1, basis1, root1,
                                               att2, basis2, root2,
                                               Wt1, Wt2, rT1, rT2);
    gather_zero<<<(NN * 16 + 255) / 256, 256, 0, stream>>>(
        entity, (const f32x4*)emb, (f32x4*)x0, (f32x4*)s, (f32x4*)cnt);
    hist_edges<<<HB, 256, 0, stream>>>(edge_type, dst, blockHist, cnt);
    colscan<<<NR, 256, 0, stream>>>(blockHist, blockPrefix, relTot);
    scanK<<<1, 256, 0, stream>>>(relTot, offs, nbG, tabR, tabS);
    scatter_sorted<<<HB, 256, 0, stream>>>(src, dst, edge_type, edge_norm,
                                           offs, blockPrefix, srcS, dstS, normS);

    // ---- layer 1 ----
    edge_mfma<<<EGRID, 256, 0, stream>>>(srcS, dstS, normS, offs,
                                         tabR, tabS, nbG, x0, Wt1, s);
    node_mfma<<<NGRID, 256, 0, stream>>>(x0, s, cnt, rT1, bias1, out, 1);

    // ---- layer 2 ----
    edge_mfma<<<EGRID, 256, 0, stream>>>(srcS, dstS, normS, offs,
                                         tabR, tabS, nbG, out, Wt2, s);
    node_mfma<<<NGRID, 256, 0, stream>>>(out, s, cnt, rT2, bias2, out, 0);
}